// Round 19
// baseline (126.425 us; speedup 1.0000x reference)
//
#include <hip/hip_runtime.h>
#include <hip/hip_bf16.h>
#include <cstdint>
#include <cstddef>

#define I_F   1024
#define O_F   1024
#define BATCH 4096
#define KDIM  9216   // 9 * 1024 : j-major (j=0 base/swish, j=1..8 spline bases)
#define EPSC  1e-7f

typedef __bf16 bf16;
typedef __bf16 bf16x4 __attribute__((ext_vector_type(4)));
typedef __bf16 bf16x8 __attribute__((ext_vector_type(8)));
typedef float  f32x4  __attribute__((ext_vector_type(4)));

// ---------------------------------------------------------------------------
// Kernel 1 (fused prep): blocks [0,512) -> weight prep, [512,4608) -> acts.
// ---------------------------------------------------------------------------
__global__ __launch_bounds__(256) void prep_kernel(const float* __restrict__ x,
                                                   const float* __restrict__ grid,
                                                   const float* __restrict__ w,
                                                   const float* __restrict__ ss,
                                                   const float* __restrict__ bs,
                                                   bf16* __restrict__ A,
                                                   bf16* __restrict__ Wt) {
    if (blockIdx.x < 512) {
        // ---- weight prep ----
        int g = blockIdx.x * 256 + threadIdx.x;      // 131072 threads
        int i  = g & 1023;
        int o0 = (g >> 10) << 3;                     // 8 o per thread
        size_t io0 = (size_t)i * 1024 + o0;
        f32x4 ssv0 = *(const f32x4*)(ss + io0);
        f32x4 ssv1 = *(const f32x4*)(ss + io0 + 4);
        f32x4 bsv0 = *(const f32x4*)(bs + io0);
        f32x4 bsv1 = *(const f32x4*)(bs + io0 + 4);
#pragma unroll
        for (int oo = 0; oo < 8; ++oo) {
            int o = o0 + oo;
            float scale = (oo < 4) ? ssv0[oo & 3] : ssv1[oo & 3];
            float base  = (oo < 4) ? bsv0[oo & 3] : bsv1[oo & 3];
            const float* wp = w + (io0 + oo) * 8;
            f32x4 w0 = *(const f32x4*)(wp);
            f32x4 w1 = *(const f32x4*)(wp + 4);

            bf16* outp = Wt + (size_t)o * KDIM + i;
            outp[0] = (bf16)base;
#pragma unroll
            for (int k = 0; k < 4; ++k) outp[(size_t)(k + 1) * 1024] = (bf16)(w0[k] * scale);
#pragma unroll
            for (int k = 0; k < 4; ++k) outp[(size_t)(k + 5) * 1024] = (bf16)(w1[k] * scale);
        }
    } else {
        // ---- activations ----
        int t  = (blockIdx.x - 512) * 256 + threadIdx.x;  // 1,048,576 threads
        int b  = t >> 8;
        int i0 = (t & 255) << 2;
        f32x4 xv4 = *(const f32x4*)(x + (size_t)b * I_F + i0);

        float g[12];
#pragma unroll
        for (int j = 0; j < 12; ++j) g[j] = grid[j];
        float r1[11], r2[10], r3[9];
#pragma unroll
        for (int j = 0; j < 11; ++j) r1[j] = __builtin_amdgcn_rcpf(g[j + 1] - g[j] + EPSC);
#pragma unroll
        for (int j = 0; j < 10; ++j) r2[j] = __builtin_amdgcn_rcpf(g[j + 2] - g[j] + EPSC);
#pragma unroll
        for (int j = 0; j < 9;  ++j) r3[j] = __builtin_amdgcn_rcpf(g[j + 3] - g[j] + EPSC);

        float sw[4];
        float bs8[4][8];
#pragma unroll
        for (int e = 0; e < 4; ++e) {
            float xv = xv4[e];
            float bas[11];
#pragma unroll
            for (int j = 0; j < 11; ++j)
                bas[j] = (xv >= g[j] && xv < g[j + 1]) ? 1.0f : 0.0f;
#pragma unroll
            for (int j = 0; j < 10; ++j)
                bas[j] = (xv - g[j]) * r1[j] * bas[j] + (g[j + 2] - xv) * r1[j + 1] * bas[j + 1];
#pragma unroll
            for (int j = 0; j < 9; ++j)
                bas[j] = (xv - g[j]) * r2[j] * bas[j] + (g[j + 3] - xv) * r2[j + 1] * bas[j + 1];
#pragma unroll
            for (int j = 0; j < 8; ++j)
                bas[j] = (xv - g[j]) * r3[j] * bas[j] + (g[j + 4] - xv) * r3[j + 1] * bas[j + 1];
#pragma unroll
            for (int k = 0; k < 8; ++k) bs8[e][k] = bas[k];
            float sig = 1.0f / (1.0f + __expf(-xv));
            sw[e] = xv * sig;
        }

        bf16* outp = A + (size_t)b * KDIM + i0;
        *(bf16x4*)(outp) = (bf16x4){(bf16)sw[0], (bf16)sw[1], (bf16)sw[2], (bf16)sw[3]};
#pragma unroll
        for (int k = 0; k < 8; ++k)
            *(bf16x4*)(outp + (size_t)(k + 1) * 1024) =
                (bf16x4){(bf16)bs8[0][k], (bf16)bs8[1][k], (bf16)bs8[2][k], (bf16)bs8[3][k]};
    }
}

// ---------------------------------------------------------------------------
__device__ __forceinline__ void load_lds16(const bf16* g, bf16* l) {
    __builtin_amdgcn_global_load_lds(
        (__attribute__((address_space(1))) void*)g,
        (__attribute__((address_space(3))) void*)l, 16, 0, 0);
}

// ---------------------------------------------------------------------------
// Kernel 2a: GEMM, BK=32 double-buffer 64KB LDS, 2 blocks/CU.
// R19 = R18's kernel launched with split=8 -> 512 blocks = 2 blocks/CU
// (R18's grid was 256 -> no co-resident partner; occupancy never rose).
// Co-resident block at an independent K-phase fills barrier-convergence
// and vmcnt tails (m114). Per-wave shape, swizzle pair, decode: proven.
// ---------------------------------------------------------------------------
__global__ __launch_bounds__(512, 2) void gemm32_kernel(const bf16* __restrict__ A,
                                                        const bf16* __restrict__ Wt,
                                                        bf16* __restrict__ parts,
                                                        int split, int ktiles) {  // BK=32 units
    __shared__ __align__(16) bf16 SA[2][8192];   // 2 slots x 16KB (256 rows x 32 k)
    __shared__ __align__(16) bf16 SB[2][8192];

    const int t    = threadIdx.x;
    const int lane = t & 63;
    const int w    = t >> 6;           // 0..7

    // XCD-chunked decode: each XCD owns a contiguous L-range sharing tn panels.
    const int nwg8 = gridDim.x >> 3;
    const int L    = (blockIdx.x & 7) * nwg8 + (blockIdx.x >> 3);
    const int nper = split << 4;
    const int tn   = L / nper;
    const int rem  = L - tn * nper;
    const int s    = rem >> 4;
    const int tm   = rem & 15;

    const int row0 = tm << 8;
    const int col0 = tn << 8;
    const size_t k0 = (size_t)s * ktiles * 32;

    // staging: content(phys unit p, row r) = logical unit p ^ ((r>>1)&3)
    const int sr = lane >> 2;
    const int lc = (lane & 3) ^ ((lane >> 3) & 3);
    const bf16* gA0 = A  + (size_t)(row0 + w * 16 + sr) * KDIM + k0 + lc * 8;
    const bf16* gB0 = Wt + (size_t)(col0 + w * 16 + sr) * KDIM + k0 + lc * 8;

    const int wm  = w >> 2;
    const int wn  = w & 3;
    const int r15 = lane & 15;
    const int g4  = lane >> 4;
    const int swb = (r15 >> 1) & 3;
    const int cp  = ((g4 ^ swb) << 3);

    f32x4 acc[8][4];
#pragma unroll
    for (int mt = 0; mt < 8; ++mt)
#pragma unroll
        for (int nt = 0; nt < 4; ++nt) acc[mt][nt] = (f32x4){0.f, 0.f, 0.f, 0.f};

    auto stage = [&](int j) {
        const int sl = j & 1;
        const bf16* pa = gA0 + (size_t)j * 32;
        const bf16* pb = gB0 + (size_t)j * 32;
        load_lds16(pa,                      &SA[sl][w * 512]);
        load_lds16(pa + (size_t)128 * KDIM, &SA[sl][4096 + w * 512]);
        load_lds16(pb,                      &SB[sl][w * 512]);
        load_lds16(pb + (size_t)128 * KDIM, &SB[sl][4096 + w * 512]);
    };

    auto frag_load = [&](int sl, bf16x8 (&af)[8], bf16x8 (&bv)[4]) {
        af[0] = *(const bf16x8*)&SA[sl][(wm * 128 + 0 * 16 + r15) * 32 + cp];
#pragma unroll
        for (int nt = 0; nt < 4; ++nt)
            bv[nt] = *(const bf16x8*)&SB[sl][(wn * 64 + nt * 16 + r15) * 32 + cp];
#pragma unroll
        for (int mt = 1; mt < 8; ++mt)
            af[mt] = *(const bf16x8*)&SA[sl][(wm * 128 + mt * 16 + r15) * 32 + cp];
    };

    auto do_mfma = [&](bf16x8 (&af)[8], bf16x8 (&bv)[4]) {
        __builtin_amdgcn_s_setprio(1);
#pragma unroll
        for (int mt = 0; mt < 8; ++mt)
#pragma unroll
            for (int nt = 0; nt < 4; ++nt)
                acc[mt][nt] = __builtin_amdgcn_mfma_f32_16x16x32_bf16(
                    af[mt], bv[nt], acc[mt][nt], 0, 0, 0);
        __builtin_amdgcn_s_setprio(0);
    };

    stage(0);
    for (int j = 0; j < ktiles; ++j) {
        asm volatile("s_waitcnt vmcnt(0)" ::: "memory");
        __builtin_amdgcn_s_barrier();
        asm volatile("" ::: "memory");
        bf16x8 af[8], bv[4];
        frag_load(j & 1, af, bv);
        if (j + 1 < ktiles) stage(j + 1);
        do_mfma(af, bv);
    }

    bf16* cp2 = parts + (size_t)s * BATCH * O_F
              + (size_t)(row0 + wm * 128) * O_F + col0 + wn * 64 + r15;
#pragma unroll
    for (int mt = 0; mt < 8; ++mt)
#pragma unroll
        for (int nt = 0; nt < 4; ++nt)
#pragma unroll
            for (int r = 0; r < 4; ++r)
                cp2[(size_t)(mt * 16 + g4 * 4 + r) * O_F + nt * 16] = (bf16)acc[mt][nt][r];
}

// ---------------------------------------------------------------------------
// Kernel 2b (fallback, R16-proven): BK=64 double-buffer 128KB, 1 block/CU.
// ---------------------------------------------------------------------------
__global__ __launch_bounds__(512, 1) void gemm64_kernel(const bf16* __restrict__ A,
                                                        const bf16* __restrict__ Wt,
                                                        bf16* __restrict__ parts,
                                                        int split, int ktiles) {  // BK=64 units
    __shared__ __align__(16) bf16 SA[2][16384];
    __shared__ __align__(16) bf16 SB[2][16384];

    const int t    = threadIdx.x;
    const int lane = t & 63;
    const int w    = t >> 6;

    const int nwg8 = gridDim.x >> 3;
    const int L    = (blockIdx.x & 7) * nwg8 + (blockIdx.x >> 3);
    const int nper = split << 4;
    const int tn   = L / nper;
    const int rem  = L - tn * nper;
    const int s    = rem >> 4;
    const int tm   = rem & 15;

    const int row0 = tm << 8;
    const int col0 = tn << 8;
    const size_t k0 = (size_t)s * ktiles * 64;

    const int sr8 = lane >> 3;
    const int lc  = (lane & 7) ^ sr8;
    const bf16* gA0 = A  + (size_t)(row0 + w * 32 + sr8) * KDIM + k0 + lc * 8;
    const bf16* gB0 = Wt + (size_t)(col0 + w * 32 + sr8) * KDIM + k0 + lc * 8;

    const int wm  = w >> 2;
    const int wn  = w & 3;
    const int r15 = lane & 15;
    const int g4  = lane >> 4;
    const int rx7 = r15 & 7;

    f32x4 acc[8][4];
#pragma unroll
    for (int mt = 0; mt < 8; ++mt)
#pragma unroll
        for (int nt = 0; nt < 4; ++nt) acc[mt][nt] = (f32x4){0.f, 0.f, 0.f, 0.f};

    auto stage = [&](int j) {
        const int sl = j & 1;
        const bf16* pa = gA0 + (size_t)j * 64;
        const bf16* pb = gB0 + (size_t)j * 64;
#pragma unroll
        for (int q = 0; q < 4; ++q)
            load_lds16(pa + (size_t)(q * 8) * KDIM, &SA[sl][(w * 32 + q * 8) * 64]);
#pragma unroll
        for (int q = 0; q < 4; ++q)
            load_lds16(pb + (size_t)(q * 8) * KDIM, &SB[sl][(w * 32 + q * 8) * 64]);
    };

    auto frag_load = [&](int sl, int ks, bf16x8 (&af)[8], bf16x8 (&bv)[4]) {
        const int cp = (((ks * 4 + g4) ^ rx7) << 3);
        af[0] = *(const bf16x8*)&SA[sl][(wm * 128 + 0 * 16 + r15) * 64 + cp];
#pragma unroll
        for (int nt = 0; nt < 4; ++nt)
            bv[nt] = *(const bf16x8*)&SB[sl][(wn * 64 + nt * 16 + r15) * 64 + cp];
#pragma unroll
        for (int mt = 1; mt < 8; ++mt)
            af[mt] = *(const bf16x8*)&SA[sl][(wm * 128 + mt * 16 + r15) * 64 + cp];
    };

    auto do_mfma = [&](bf16x8 (&af)[8], bf16x8 (&bv)[4]) {
        __builtin_amdgcn_s_setprio(1);
#pragma unroll
        for (int mt = 0; mt < 8; ++mt)
#pragma unroll
            for (int nt = 0; nt < 4; ++nt)
                acc[mt][nt] = __builtin_amdgcn_mfma_f32_16x16x32_bf16(
                    af[mt], bv[nt], acc[mt][nt], 0, 0, 0);
        __builtin_amdgcn_s_setprio(0);
    };

    stage(0);
    for (int j = 0; j < ktiles; ++j) {
        asm volatile("s_waitcnt vmcnt(0)" ::: "memory");
        __builtin_amdgcn_s_barrier();
        asm volatile("" ::: "memory");
        bf16x8 af0[8], bv0[4], af1[8], bv1[4];
        frag_load(j & 1, 0, af0, bv0);
        if (j + 1 < ktiles) stage(j + 1);
        do_mfma(af0, bv0);
        frag_load(j & 1, 1, af1, bv1);
        do_mfma(af1, bv1);
    }

    bf16* cp2 = parts + (size_t)s * BATCH * O_F
              + (size_t)(row0 + wm * 128) * O_F + col0 + wn * 64 + r15;
#pragma unroll
    for (int mt = 0; mt < 8; ++mt)
#pragma unroll
        for (int nt = 0; nt < 4; ++nt)
#pragma unroll
            for (int r = 0; r < 4; ++r)
                cp2[(size_t)(mt * 16 + g4 * 4 + r) * O_F + nt * 16] = (bf16)acc[mt][nt][r];
}

// ---------------------------------------------------------------------------
// Kernel 3: out = sum(parts[0..np))   (split-K reduce), bf16 partials -> f32
// ---------------------------------------------------------------------------
__global__ __launch_bounds__(256) void add_kernel(float* __restrict__ out,
                                                  const bf16* __restrict__ parts,
                                                  int np) {
    int t = blockIdx.x * 256 + threadIdx.x;      // 1,048,576 threads, 4 f32 each
    f32x4 a = {0.f, 0.f, 0.f, 0.f};
    for (int p = 0; p < np; ++p) {
        bf16x4 b = *((const bf16x4*)(parts + (size_t)p * BATCH * O_F) + t);
#pragma unroll
        for (int e = 0; e < 4; ++e) a[e] += (float)b[e];
    }
    *((f32x4*)out + t) = a;
}

// ---------------------------------------------------------------------------
extern "C" void kernel_launch(void* const* d_in, const int* in_sizes, int n_in,
                              void* d_out, int out_size, void* d_ws, size_t ws_size,
                              hipStream_t stream) {
    const float* x    = (const float*)d_in[0];
    const float* grid = (const float*)d_in[1];
    const float* w    = (const float*)d_in[2];
    const float* ss   = (const float*)d_in[3];
    const float* bs   = (const float*)d_in[4];
    float* out = (float*)d_out;

    const size_t nA = (size_t)BATCH * KDIM * 2;   // 75.5 MB
    const size_t nW = (size_t)O_F   * KDIM * 2;   // 18.9 MB
    const size_t nP = (size_t)BATCH * O_F  * 2;   // 8.39 MB per bf16 partial

    bf16* A  = (bf16*)d_ws;
    bf16* Wt = (bf16*)((char*)d_ws + nA);
    bf16* parts = (bf16*)((char*)d_ws + nA + nW);

    prep_kernel<<<4608, 256, 0, stream>>>(x, grid, w, ss, bs, A, Wt);

    if (ws_size >= nA + nW + 8 * nP) {
        // 512 blocks = 2 blocks/CU (the point of this round)
        gemm32_kernel<<<64 * 8, 512, 0, stream>>>(A, Wt, parts, 8, 288 / 8);
        add_kernel<<<(BATCH * O_F / 4) / 256, 256, 0, stream>>>(out, parts, 8);
    } else if (ws_size >= nA + nW + 4 * nP) {
        gemm64_kernel<<<64 * 4, 512, 0, stream>>>(A, Wt, parts, 4, 144 / 4);
        add_kernel<<<(BATCH * O_F / 4) / 256, 256, 0, stream>>>(out, parts, 4);
    } else {
        gemm64_kernel<<<64 * 2, 512, 0, stream>>>(A, Wt, parts, 2, 144 / 2);
        add_kernel<<<(BATCH * O_F / 4) / 256, 256, 0, stream>>>(out, parts, 2);
    }
}